// Round 7
// baseline (101.498 us; speedup 1.0000x reference)
//
#include <hip/hip_runtime.h>
#include <math.h>

#define F_    16
#define NV_   4096
#define NT_   512
#define M_    4096
#define PPF_  (NV_ + NT_)        // 4608 points per frame
#define NPTS_ (F_ * PPF_)        // 73728 total points
#define SCALE_INV 10.0f          // 1 / 0.1

#define TPB   256
#define PTSB  72                 // 64 blocks/frame (no straddle); grid 1024 = 4 blocks/CU exact
#define NBLK  (NPTS_ / PTSB)     // 1024
#define NG    64                 // model groups (g = t>>2, 4 lanes each) -> 64 ds_reads/wave (halved)
#define MPG   (M_ / NG)          // 64 models per group
#define CHM   16                 // models per group per chunk
#define NCH   (MPG / CHM)        // 4 chunks
#define FG    68                 // feat row stride in float4: [m][68] -> (4m+g)&7 spans quads 2-way = free
#define PPL   18                 // points per lane (4 point-lanes x 18 = 72)
#define NPR   9                  // f32 pairs per lane

typedef float v2f __attribute__((ext_vector_type(2)));

// ---------------------------------------------------------------- pose math
__device__ inline void rot_from_omega(float ox, float oy, float oz, float dt,
                                      float* R) {
    // R = I + sin(theta*dt)*S + (1-cos(theta*dt))*S^2,  S = skew(omega/max(theta,1e-8))
    float theta = sqrtf(ox * ox + oy * oy + oz * oz);
    float inv = 1.0f / fmaxf(theta, 1e-8f);
    float ax = ox * inv, ay = oy * inv, az = oz * inv;
    float s = sinf(theta * dt);
    float c = 1.0f - cosf(theta * dt);
    R[0] = 1.0f - c * (ay * ay + az * az);
    R[1] = -s * az + c * ax * ay;
    R[2] =  s * ay + c * ax * az;
    R[3] =  s * az + c * ax * ay;
    R[4] = 1.0f - c * (ax * ax + az * az);
    R[5] = -s * ax + c * ay * az;
    R[6] = -s * ay + c * ax * az;
    R[7] =  s * ax + c * ay * az;
    R[8] = 1.0f - c * (ax * ax + ay * ay);
}

// ---------------------------------------------------------------- packed distance core
// 2 models (A,B) x 3 point-pairs: 18 v_pk_fma_f32 + 6 v_min3. op_sel broadcasts
// the model scalars straight out of the staged quad (r6-proven encoding):
// z-stage acc={fma(-2gz,z,w)}, y-stage +=-2gy*y, x-stage +=-2gx*x.
__device__ __forceinline__ void dist6(v2f qa01, v2f qa23, v2f qb01, v2f qb23,
                                      v2f c0a, v2f c0b, v2f c0c,
                                      v2f c1a, v2f c1b, v2f c1c,
                                      v2f c2a, v2f c2b, v2f c2c, float* dmp) {
    v2f A0, A1, A2, B0, B1, B2;
    asm("v_pk_fma_f32 %0, %7, %16, %7 op_sel:[0,0,1] op_sel_hi:[0,1,1]\n\t"
        "v_pk_fma_f32 %1, %7, %17, %7 op_sel:[0,0,1] op_sel_hi:[0,1,1]\n\t"
        "v_pk_fma_f32 %2, %7, %18, %7 op_sel:[0,0,1] op_sel_hi:[0,1,1]\n\t"
        "v_pk_fma_f32 %3, %9, %16, %9 op_sel:[0,0,1] op_sel_hi:[0,1,1]\n\t"
        "v_pk_fma_f32 %4, %9, %17, %9 op_sel:[0,0,1] op_sel_hi:[0,1,1]\n\t"
        "v_pk_fma_f32 %5, %9, %18, %9 op_sel:[0,0,1] op_sel_hi:[0,1,1]\n\t"
        "v_pk_fma_f32 %0, %6, %13, %0 op_sel:[1,0,0] op_sel_hi:[1,1,1]\n\t"
        "v_pk_fma_f32 %1, %6, %14, %1 op_sel:[1,0,0] op_sel_hi:[1,1,1]\n\t"
        "v_pk_fma_f32 %2, %6, %15, %2 op_sel:[1,0,0] op_sel_hi:[1,1,1]\n\t"
        "v_pk_fma_f32 %3, %8, %13, %3 op_sel:[1,0,0] op_sel_hi:[1,1,1]\n\t"
        "v_pk_fma_f32 %4, %8, %14, %4 op_sel:[1,0,0] op_sel_hi:[1,1,1]\n\t"
        "v_pk_fma_f32 %5, %8, %15, %5 op_sel:[1,0,0] op_sel_hi:[1,1,1]\n\t"
        "v_pk_fma_f32 %0, %6, %10, %0 op_sel:[0,0,0] op_sel_hi:[0,1,1]\n\t"
        "v_pk_fma_f32 %1, %6, %11, %1 op_sel:[0,0,0] op_sel_hi:[0,1,1]\n\t"
        "v_pk_fma_f32 %2, %6, %12, %2 op_sel:[0,0,0] op_sel_hi:[0,1,1]\n\t"
        "v_pk_fma_f32 %3, %8, %10, %3 op_sel:[0,0,0] op_sel_hi:[0,1,1]\n\t"
        "v_pk_fma_f32 %4, %8, %11, %4 op_sel:[0,0,0] op_sel_hi:[0,1,1]\n\t"
        "v_pk_fma_f32 %5, %8, %12, %5 op_sel:[0,0,0] op_sel_hi:[0,1,1]"
        : "=&v"(A0), "=&v"(A1), "=&v"(A2), "=&v"(B0), "=&v"(B1), "=&v"(B2)
        : "v"(qa01), "v"(qa23), "v"(qb01), "v"(qb23),
          "v"(c0a), "v"(c0b), "v"(c0c),
          "v"(c1a), "v"(c1b), "v"(c1c),
          "v"(c2a), "v"(c2b), "v"(c2c));
    dmp[0] = fminf(fminf(A0.x, B0.x), dmp[0]);
    dmp[1] = fminf(fminf(A0.y, B0.y), dmp[1]);
    dmp[2] = fminf(fminf(A1.x, B1.x), dmp[2]);
    dmp[3] = fminf(fminf(A1.y, B1.y), dmp[3]);
    dmp[4] = fminf(fminf(A2.x, B2.x), dmp[4]);
    dmp[5] = fminf(fminf(A2.y, B2.y), dmp[5]);
}

// ---------------------------------------------------------------- prep (ws is free: poison fill is unconditional)
// block 0: 16 poses (parallel step rotations + thread-0 serial compose, r2-proven
// bit-exact association). blocks 1..16: 4096 model features, chunk-linear layout.
__global__ void prep_kernel(const float* __restrict__ state,
                            const float* __restrict__ phys,
                            const float* __restrict__ dts,
                            const float* __restrict__ model,
                            float* __restrict__ ws_pose,
                            float4* __restrict__ ws_feat) {
    const int b = blockIdx.x, t = threadIdx.x;
    if (b == 0) {
        __shared__ float sRs[F_ * 9];
        __shared__ float sdt[F_ * 3];
        if (t < F_) {
            float ox, oy, oz, dt;
            if (t == 0) { ox = state[3]; oy = state[4]; oz = state[5]; dt = 1.0f; }
            else        { ox = phys[t * 12 + 9]; oy = phys[t * 12 + 10];
                          oz = phys[t * 12 + 11]; dt = dts[t]; }
            float Rs[9];
            rot_from_omega(ox, oy, oz, dt, Rs);
            for (int j = 0; j < 9; ++j) sRs[t * 9 + j] = Rs[j];
            if (t > 0) {
                sdt[t * 3 + 0] = phys[t * 12 + 6] * dt;
                sdt[t * 3 + 1] = phys[t * 12 + 7] * dt;
                sdt[t * 3 + 2] = phys[t * 12 + 8] * dt;
            }
        }
        if (t == 0) {   // same wave as writers above -> lockstep-ordered
            float R[9];
            for (int j = 0; j < 9; ++j) R[j] = sRs[j];
            float tr[3] = {state[0], state[1], state[2]};
            for (int i = 0; i < F_; ++i) {
                if (i > 0) {
                    tr[0] += sdt[i * 3 + 0];
                    tr[1] += sdt[i * 3 + 1];
                    tr[2] += sdt[i * 3 + 2];
                    float Rn[9];
                    const float* Rsp = sRs + i * 9;
                    for (int r = 0; r < 3; ++r)
                        for (int c2 = 0; c2 < 3; ++c2)
                            Rn[r * 3 + c2] = Rsp[r * 3 + 0] * R[0 + c2] +
                                             Rsp[r * 3 + 1] * R[3 + c2] +
                                             Rsp[r * 3 + 2] * R[6 + c2];
                    for (int j = 0; j < 9; ++j) R[j] = Rn[j];
                }
                float* o = ws_pose + i * 12;
                o[0] = tr[0]; o[1] = tr[1]; o[2] = tr[2];
                for (int j = 0; j < 9; ++j) o[3 + j] = R[j] * SCALE_INV;
            }
        }
    } else {
        const int id = (b - 1) * 256 + t;   // model id 0..4095 = g*64 + c*16 + m
        float gx = model[id * 3 + 0], gy = model[id * 3 + 1], gz = model[id * 3 + 2];
        const int c = (id >> 4) & 3, g = id >> 6, m = id & 15;
        ws_feat[c * 1024 + g * 16 + m] =
            make_float4(-2.0f * gx, -2.0f * gy, -2.0f * gz,
                        gx * gx + gy * gy + gz * gz);
    }
}

// ---------------------------------------------------------------- main kernel
// Round-6 evidence: stall-bound, not VALU-issue-bound. This version removes the
// serial pose prologue (reads ws), halves ds_read count (NG=64), and runs
// tail-free at exactly 4 blocks/CU (16 waves).
__global__ __launch_bounds__(TPB, 4) void chamfer_main(
    const float* __restrict__ vis, const float* __restrict__ tac,
    const float* __restrict__ ws_pose, const float4* __restrict__ ws_feat,
    float* __restrict__ out) {
    __shared__ float4 feat[CHM * FG];       // 17408 B, [m][g] g-padded
    __shared__ float  sdm2[NG * 80];        // 20480 B, [g][pl*20 + k]
    __shared__ float  spose[F_ * 12];       // 768 B
    __shared__ float  sw[4];

    const int t  = threadIdx.x;
    const int g  = t >> 2;                  // model group 0..63
    const int pl = t & 3;                   // point-lane 0..3 (18 points each)
    const int f  = blockIdx.x >> 6;         // 64 blocks/frame
    const int lbase = (blockIdx.x & 63) * PTSB;

    // ---- stage poses + chunk 0 ----
    if (t < F_ * 12) spose[t] = ws_pose[t];
#pragma unroll
    for (int j = 0; j < 4; ++j) {
        int flat = t + 256 * j;             // = g*16 + m within chunk
        feat[(flat & 15) * FG + (flat >> 4)] = ws_feat[flat];
    }
    __syncthreads();

    // ---- pose regs (uniform LDS broadcast reads) ----
    float Rr[9], trx, try_, trz;
    {
        const float* ps = spose + f * 12;
        trx = ps[0]; try_ = ps[1]; trz = ps[2];
        for (int j = 0; j < 9; ++j) Rr[j] = ps[3 + j];
    }

    // ---- transform my 18 points into packed pairs ----
    v2f c0p[NPR], c1p[NPR], c2p[NPR];
    float cn[PPL], dm[PPL];
#pragma unroll
    for (int k = 0; k < PPL; ++k) {
        int loc = lbase + pl * PPL + k;
        const float* p = (loc < NV_) ? (vis + ((size_t)f * NV_ + loc) * 3)
                                     : (tac + ((size_t)f * NT_ + (loc - NV_)) * 3);
        float d0 = p[0] - trx, d1 = p[1] - try_, d2 = p[2] - trz;
        float x = d0 * Rr[0] + d1 * Rr[3] + d2 * Rr[6];
        float y = d0 * Rr[1] + d1 * Rr[4] + d2 * Rr[7];
        float z = d0 * Rr[2] + d1 * Rr[5] + d2 * Rr[8];
        cn[k] = x * x + y * y + z * z;
        dm[k] = 3.4e38f;
        if (k & 1) { c0p[k >> 1].y = x; c1p[k >> 1].y = y; c2p[k >> 1].y = z; }
        else       { c0p[k >> 1].x = x; c1p[k >> 1].x = y; c2p[k >> 1].x = z; }
    }

    // ---- main loop: 4 chunks x 16 models/group ----
    for (int c = 0;; ++c) {
#pragma unroll 2
        for (int m = 0; m < CHM; m += 2) {
            float4 ga = feat[m * FG + g];        // 16 addrs/wave, 2/bank-quad = free
            float4 gb = feat[(m + 1) * FG + g];
            v2f qa01 = (v2f){ga.x, ga.y}, qa23 = (v2f){ga.z, ga.w};
            v2f qb01 = (v2f){gb.x, gb.y}, qb23 = (v2f){gb.z, gb.w};
            dist6(qa01, qa23, qb01, qb23, c0p[0], c0p[1], c0p[2],
                  c1p[0], c1p[1], c1p[2], c2p[0], c2p[1], c2p[2], dm);
            dist6(qa01, qa23, qb01, qb23, c0p[3], c0p[4], c0p[5],
                  c1p[3], c1p[4], c1p[5], c2p[3], c2p[4], c2p[5], dm + 6);
            dist6(qa01, qa23, qb01, qb23, c0p[6], c0p[7], c0p[8],
                  c1p[6], c1p[7], c1p[8], c2p[6], c2p[7], c2p[8], dm + 12);
        }
        if (c == NCH - 1) break;
        __syncthreads();
#pragma unroll
        for (int j = 0; j < 4; ++j) {
            int flat = t + 256 * j;
            feat[(flat & 15) * FG + (flat >> 4)] = ws_feat[(c + 1) * 1024 + flat];
        }
        __syncthreads();
    }

    // ---- per-group partials to LDS, then min over 64 groups per point ----
    {
        float* seg = &sdm2[g * 80 + pl * 20];    // 16B-aligned, 18 floats
#pragma unroll
        for (int k = 0; k < PPL; ++k) seg[k] = dm[k] + cn[k];
    }
    __syncthreads();

    float v = 0.0f;
    if (t < PTSB) {
        const int off = t + 2 * (t / 18);        // [g][pl*20+k] column for point t
        float mn = sdm2[off];
#pragma unroll 8
        for (int i = 1; i < NG; ++i) mn = fminf(mn, sdm2[i * 80 + off]);
        const int loc = lbase + t;
        const float w = (loc < NV_) ? (1.0f / NV_) : (0.1f / NT_);
        v = mn * w;
    }
#pragma unroll
    for (int off2 = 32; off2 > 0; off2 >>= 1) v += __shfl_down(v, off2);
    if ((t & 63) == 0) sw[t >> 6] = v;
    __syncthreads();
    if (t == 0) atomicAdd(out, sw[0] + sw[1] + sw[2] + sw[3]);
}

// ---------------------------------------------------------------- safety fallback (ws too small; never per evidence)
__global__ __launch_bounds__(TPB) void chamfer_fb(
    const float* __restrict__ state, const float* __restrict__ model,
    const float* __restrict__ vis, const float* __restrict__ tac,
    const float* __restrict__ phys, const float* __restrict__ dts,
    float* __restrict__ out) {
    __shared__ float sw[4];
    const int pt = blockIdx.x * TPB + threadIdx.x;
    const int f = pt / PPF_, loc = pt - f * PPF_;
    float R[9], tr[3] = {state[0], state[1], state[2]};
    rot_from_omega(state[3], state[4], state[5], 1.0f, R);
    for (int i = 1; i <= f; ++i) {
        float dt = dts[i];
        tr[0] += phys[i * 12 + 6] * dt;
        tr[1] += phys[i * 12 + 7] * dt;
        tr[2] += phys[i * 12 + 8] * dt;
        float Rs[9], Rn[9];
        rot_from_omega(phys[i * 12 + 9], phys[i * 12 + 10], phys[i * 12 + 11], dt, Rs);
        for (int r = 0; r < 3; ++r)
            for (int c2 = 0; c2 < 3; ++c2)
                Rn[r * 3 + c2] = Rs[r * 3 + 0] * R[0 + c2] +
                                 Rs[r * 3 + 1] * R[3 + c2] +
                                 Rs[r * 3 + 2] * R[6 + c2];
        for (int j = 0; j < 9; ++j) R[j] = Rn[j];
    }
    for (int j = 0; j < 9; ++j) R[j] *= SCALE_INV;
    const float* p = (loc < NV_) ? (vis + ((size_t)f * NV_ + loc) * 3)
                                 : (tac + ((size_t)f * NT_ + (loc - NV_)) * 3);
    float d0 = p[0] - tr[0], d1 = p[1] - tr[1], d2 = p[2] - tr[2];
    float x = d0 * R[0] + d1 * R[3] + d2 * R[6];
    float y = d0 * R[1] + d1 * R[4] + d2 * R[7];
    float z = d0 * R[2] + d1 * R[5] + d2 * R[8];
    float cn = x * x + y * y + z * z;
    float mn = 3.4e38f;
    for (int i = 0; i < M_; ++i) {
        float gx = model[i * 3], gy = model[i * 3 + 1], gz = model[i * 3 + 2];
        float gn = gx * gx + gy * gy + gz * gz;
        float dd = fmaf(-2.0f * gx, x, fmaf(-2.0f * gy, y, fmaf(-2.0f * gz, z, gn)));
        mn = fminf(mn, dd);
    }
    float w = (loc < NV_) ? (1.0f / NV_) : (0.1f / NT_);
    float v = (mn + cn) * w;
    for (int off = 32; off > 0; off >>= 1) v += __shfl_down(v, off);
    if ((threadIdx.x & 63) == 0) sw[threadIdx.x >> 6] = v;
    __syncthreads();
    if (threadIdx.x == 0) atomicAdd(out, sw[0] + sw[1] + sw[2] + sw[3]);
}

// ---------------------------------------------------------------- launch
// ws IS used now: the 256MB poison fill runs unconditionally (r1-r6 evidence),
// so prep-computing poses+features into ws costs nothing extra.
extern "C" void kernel_launch(void* const* d_in, const int* in_sizes, int n_in,
                              void* d_out, int out_size, void* d_ws, size_t ws_size,
                              hipStream_t stream) {
    const float* state = (const float*)d_in[0];   // (6,)
    const float* model = (const float*)d_in[1];   // (M,3)
    const float* vis   = (const float*)d_in[2];   // (F,NV,3)
    const float* tac   = (const float*)d_in[3];   // (F,NT,3)
    const float* phys  = (const float*)d_in[4];   // (F,12)
    const float* dts   = (const float*)d_in[5];   // (F,)
    float* out = (float*)d_out;

    const size_t NEED = 1024 + (size_t)M_ * sizeof(float4);  // 66.6 KB
    hipMemsetAsync(out, 0, sizeof(float), stream);
    if (ws_size >= NEED) {
        float*  ws_pose = (float*)d_ws;
        float4* ws_feat = (float4*)((char*)d_ws + 1024);
        prep_kernel<<<17, 256, 0, stream>>>(state, phys, dts, model, ws_pose, ws_feat);
        chamfer_main<<<NBLK, TPB, 0, stream>>>(vis, tac, ws_pose, ws_feat, out);
    } else {
        chamfer_fb<<<NPTS_ / TPB, TPB, 0, stream>>>(state, model, vis, tac, phys,
                                                    dts, out);
    }
}